// Round 15
// baseline (426.159 us; speedup 1.0000x reference)
//
#include <hip/hip_runtime.h>

typedef __bf16 bf16x8 __attribute__((ext_vector_type(8)));
typedef float  f32x4  __attribute__((ext_vector_type(4)));

// ---- weight regions in g_wb (bf16 element offsets), repacked into 16KB k-slices,
// each split into two 8KB mt-HALVES ----
// Slice s, half h holds W[m][k] for m = w*32 + h*16 + l15, k = s*32 + lq*8 + kk at
// j = h*4096 + w*512 + lq*128 + l15*8 + kk (j within the 8192-short slice).
// Wave-ownership invariant (8 waves): wave w DMAs half bytes [w*1024, +1024) and reads
// exactly those bytes back -> no barriers for weight staging, only per-wave counted vmcnt.
// Pipeline: 2-slot LDS ring of halves (depth-1, vmcnt(1)) -- depth proven a dead axis
// (r10 vs r14); LDS saved buys 3 blocks/CU.
#define OFF_DEC1  0
#define OFF_DEC2  65536
#define OFF_PCONV 131072
#define OFF_PLIN  196608   // rows >=255 zeroed (w_plin is 255x256)
#define OFF_UP1   262144   // 9 slices (K=288, k>=264 zeroed; w_up1 is 256x264)
#define OFF_UR1   335872
#define OFF_UR2   401408
#define OFF_UOUT  466944   // 8 chunks x 8 slices (chunk c = w_uout rows c*256..c*256+255)
#define WB_TOTAL  991232

__device__ __align__(16) unsigned short g_wb[WB_TOTAL];

__device__ __forceinline__ unsigned short f2bf(float f) {
  union { float f; unsigned u; } c; c.f = f;
  unsigned u = c.u + 0x7FFFu + ((c.u >> 16) & 1u);   // RNE, finite inputs only
  return (unsigned short)(u >> 16);
}
__device__ __forceinline__ float bf2f(unsigned short b) {
  union { unsigned u; float f; } c; c.u = ((unsigned)b) << 16;
  return c.f;
}
__device__ __forceinline__ float reqf(float v) {      // requant: x/256 clipped to int8 range
  return fminf(fmaxf(v * 0.00390625f, -128.f), 127.f);
}

// ---- weight fp32 -> bf16 preconvert + half-slice repack (runs every launch) ----
__global__ void wconv_kernel(const float* __restrict__ wd1, const float* __restrict__ wd2,
                             const float* __restrict__ wpc, const float* __restrict__ wpl,
                             const float* __restrict__ wu1, const float* __restrict__ wr1,
                             const float* __restrict__ wr2, const float* __restrict__ wuo) {
  int t = blockIdx.x * 256 + threadIdx.x;
  if (t >= WB_TOTAL) return;
  const float* src; int local, Ksrc = 256, Msrc = 256, rowOff = 0;
  if      (t < OFF_DEC2)  { src = wd1; local = t; }
  else if (t < OFF_PCONV) { src = wd2; local = t - OFF_DEC2; }
  else if (t < OFF_PLIN)  { src = wpc; local = t - OFF_PCONV; }
  else if (t < OFF_UP1)   { src = wpl; local = t - OFF_PLIN; Msrc = 255; }
  else if (t < OFF_UR1)   { src = wu1; local = t - OFF_UP1; Ksrc = 264; }
  else if (t < OFF_UR2)   { src = wr1; local = t - OFF_UR1; }
  else if (t < OFF_UOUT)  { src = wr2; local = t - OFF_UR2; }
  else { local = t - OFF_UOUT; int c = local >> 16; local &= 65535; src = wuo; rowOff = c * 256; }
  const int s = local >> 13, j = local & 8191;
  const int h = j >> 12, wv = (j >> 9) & 7, lq = (j >> 7) & 3;
  const int l15 = (j >> 3) & 15, kk = j & 7;
  const int m = wv * 32 + h * 16 + l15;
  const int k = s * 32 + lq * 8 + kk;
  float v = (m < Msrc && k < Ksrc) ? src[(size_t)(rowOff + m) * Ksrc + k] : 0.f;
  g_wb[t] = f2bf(v);
}

// ---- MFMA mapping (weights = A, acts = B) ----
// D-frag: col = l15 -> ACT ROW ; row = lq*4 + r -> OUTPUT CHANNEL offset within mt-block
// LDS act tile [64][256] bf16, byte = row*512 + (colbyte ^ ((row&15)<<4))
// (16-slot swizzle: act-frag reads go 8-way -> 4-way bank aliasing vs (row&7))

__device__ __forceinline__ void zero_acc(f32x4 (&acc)[2][4]) {
#pragma unroll
  for (int i = 0; i < 2; ++i)
#pragma unroll
    for (int j = 0; j < 4; ++j) acc[i][j] = (f32x4){0.f, 0.f, 0.f, 0.f};
}

__device__ __forceinline__ void prelu_acc(f32x4 (&acc)[2][4], float a) {
#pragma unroll
  for (int i = 0; i < 2; ++i)
#pragma unroll
    for (int j = 0; j < 4; ++j)
#pragma unroll
      for (int r = 0; r < 4; ++r) {
        float v = acc[i][j][r];
        acc[i][j][r] = v >= 0.f ? v : a * v;
      }
}

// DMA one 8 KB weight HALF into LDS: per wave, 1 issue x 64 lanes x 16 B into the
// wave's own 1 KB region (shorts [w*512, +512)).
__device__ __forceinline__ void stageWh(const unsigned short* __restrict__ src,
                                        unsigned short* dst, int w, int l) {
  const int off = w * 512 + l * 8;
  __builtin_amdgcn_global_load_lds(
      (const __attribute__((address_space(1))) unsigned*)(src + off),
      (__attribute__((address_space(3))) unsigned*)(dst + off),
      16, 0, 0);
}

// Full GEMM over NKS slices = 2*NKS half-steps on a 2-slot ring, 1 half in flight.
// Each GEMM has an even number of half-steps, so every GEMM's half 0 lands in slot 0.
// wnext = next GEMM's half-0 source (prefetch chains across GEMMs), or nullptr.
template<int NKS, bool BIN_TAIL>
__device__ __forceinline__ void gemm_ring(const unsigned short* __restrict__ wcur,
                                          const unsigned short* __restrict__ wnext,
                                          unsigned short* sW,
                                          const unsigned short* sAct,
                                          const unsigned short* sBinA,
                                          int w, int l, int l15, int lq,
                                          f32x4 (&acc)[2][4]) {
  bf16x8 af[4];
#pragma unroll
  for (int hs = 0; hs < 2 * NKS; ++hs) {
    const int ks = hs >> 1, mt = hs & 1;
    const int slot = hs & 1, nslot = slot ^ 1;
    if (hs + 1 < 2 * NKS) {
      stageWh(wcur + (hs + 1) * 4096, sW + nslot * 4096, w, l);
      asm volatile("s_waitcnt vmcnt(1)" ::: "memory");   // half hs landed; hs+1 in flight
    } else if (wnext) {
      stageWh(wnext, sW + nslot * 4096, w, l);
      asm volatile("s_waitcnt vmcnt(1)" ::: "memory");
    } else {
      asm volatile("s_waitcnt vmcnt(0)" ::: "memory");   // final GEMM tail: drain
    }
    __builtin_amdgcn_sched_barrier(0);
    if (mt == 0) {     // act fragments serve both halves of a slice
      if (BIN_TAIL && ks == NKS - 1) {
#pragma unroll
        for (int nt = 0; nt < 4; ++nt)
          af[nt] = *(const bf16x8*)(sBinA + (nt * 16 + l15) * 32 + lq * 8);
      } else {
        const int kb = ks * 64 + lq * 16;
#pragma unroll
        for (int nt = 0; nt < 4; ++nt) {
          const int row = nt * 16 + l15;
          af[nt] = *(const bf16x8*)((const char*)sAct + row * 512 + (kb ^ ((row & 15) << 4)));
        }
      }
    }
    __builtin_amdgcn_s_setprio(1);
    bf16x8 bfr = *(const bf16x8*)(sW + slot * 4096 + w * 512 + lq * 128 + l15 * 8);
#pragma unroll
    for (int nt = 0; nt < 4; ++nt)
      acc[mt][nt] = __builtin_amdgcn_mfma_f32_16x16x32_bf16(bfr, af[nt], acc[mt][nt], 0, 0, 0);
    __builtin_amdgcn_s_setprio(0);
  }
}

// acc -> requant -> bf16 -> swizzled LDS act tile; one ds_write_b64 per (nt,mt)
__device__ __forceinline__ void stage_rq(const f32x4 (&acc)[2][4], unsigned short* dst,
                                         int w, int l15, int lq) {
#pragma unroll
  for (int nt = 0; nt < 4; ++nt) {
    const int row = nt * 16 + l15;
    const int swz = (row & 15) << 4;
#pragma unroll
    for (int mt = 0; mt < 2; ++mt) {
      const int ch2 = (w * 32 + mt * 16 + lq * 4) * 2;   // byte offset (8B aligned)
      ushort4 b4;
      b4.x = f2bf(reqf(acc[mt][nt][0]));
      b4.y = f2bf(reqf(acc[mt][nt][1]));
      b4.z = f2bf(reqf(acc[mt][nt][2]));
      b4.w = f2bf(reqf(acc[mt][nt][3]));
      *(ushort4*)((char*)dst + row * 512 + (ch2 ^ swz)) = b4;
    }
  }
}

// uout chunk epilogue: mask by bin, f32x4 stores
__device__ __forceinline__ void store_chunk(const f32x4 (&acc)[2][4], float* __restrict__ out,
                                            const unsigned short* sBinA, int r0, int N,
                                            int c, int w, int l15, int lq) {
#pragma unroll
  for (int nt = 0; nt < 4; ++nt) {
    const int row = nt * 16 + l15;
    if ((r0 + row) < N) {
      const float m = sBinA[row * 32 + c] ? 1.f : 0.f;
      float* rp = out + (size_t)(r0 + row) * 2048 + c * 256;
#pragma unroll
      for (int mt = 0; mt < 2; ++mt) {
        const int ch0 = w * 32 + mt * 16 + lq * 4;
        f32x4 v;
        v[0] = acc[mt][nt][0] * m; v[1] = acc[mt][nt][1] * m;
        v[2] = acc[mt][nt][2] * m; v[3] = acc[mt][nt][3] * m;
        *(f32x4*)(rp + ch0) = v;
      }
    }
  }
}

__global__ __launch_bounds__(512, 6) void fused_kernel(
    const float* __restrict__ x, const int* __restrict__ cur_bin,
    const float* __restrict__ a_dec, const float* __restrict__ a_pconv,
    const float* __restrict__ a_up1, const float* __restrict__ a_ur,
    float* __restrict__ out, int N)
{
  __shared__ __align__(16) unsigned short sA[64 * 256];     // 32 KB act buffer (in place)
  __shared__ __align__(16) unsigned short sW[2 * 4096];     // 16 KB: 2-slot half ring
  __shared__ __align__(16) unsigned short sBinA[64 * 32];   // bin tile, k>=8 zeroed (4 KB)
  // total 52 KB -> 3 blocks/CU; VGPR cap 85 (r14 natural was 64, fits)

  const int tid = threadIdx.x;
  const int w = tid >> 6, l = tid & 63;
  const int l15 = l & 15, lq = l >> 4;
  const int r0 = blockIdx.x * 64;
  const size_t PRED_BASE = (size_t)N * 2048;
  const size_t OCT_BASE  = PRED_BASE + (size_t)N * 255;

  const float A_DEC = a_dec[0], A_PCONV = a_pconv[0], A_UP1 = a_up1[0], A_UR = a_ur[0];

  // prologue: G1 half 0 into ring slot 0; overlaps act staging below
  stageWh(g_wb + OFF_DEC1, sW, w, l);

  // ---- stage bin (bf16-padded B-tile; 0/1 values exact in bf16) ----
  for (int i = tid; i < 64 * 32; i += 512) {
    const int row = i >> 5, j = i & 31;
    float bv = 0.f;
    if (j < 8 && (r0 + row) < N) bv = (float)cur_bin[(size_t)(r0 + row) * 8 + j];
    sBinA[i] = (j < 8) ? f2bf(bv) : (unsigned short)0;
  }
  // ---- cur_oct ----
  if (tid < 64 && (r0 + tid) < N) {
    int s = 0;
#pragma unroll
    for (int j = 0; j < 8; ++j) s += cur_bin[(size_t)(r0 + tid) * 8 + j] << j;
    out[OCT_BASE + r0 + tid] = (float)(s - 1);
  }
  // ---- stage requant(x) -> sA ----
#pragma unroll
  for (int it = 0; it < 8; ++it) {
    const int e = it * 2048 + tid * 4;
    const int row = e >> 8, col = e & 255;
    float4 xv = make_float4(0.f, 0.f, 0.f, 0.f);
    if ((r0 + row) < N) xv = *(const float4*)(x + (size_t)(r0 + row) * 256 + col);
    ushort4 b4;
    b4.x = f2bf(reqf(xv.x)); b4.y = f2bf(reqf(xv.y));
    b4.z = f2bf(reqf(xv.z)); b4.w = f2bf(reqf(xv.w));
    *(ushort4*)((char*)sA + row * 512 + ((col * 2) ^ ((row & 15) << 4))) = b4;
  }
  __syncthreads();   // drains prologue DMA + act/bin visibility

  f32x4 acc[2][4];

  // ---- G1: dec1 ----
  zero_acc(acc);
  gemm_ring<8, false>(g_wb + OFF_DEC1, g_wb + OFF_DEC2, sW, sA, sBinA, w, l, l15, lq, acc);
  prelu_acc(acc, A_DEC);
  __syncthreads();
  stage_rq(acc, sA, w, l15, lq);
  __syncthreads();

  // ---- G2: dec2 + residual -> rec, stage rq(rec) -> sA ----
  zero_acc(acc);
  gemm_ring<8, false>(g_wb + OFF_DEC2, g_wb + OFF_UP1, sW, sA, sBinA, w, l, l15, lq, acc);
  __syncthreads();
#pragma unroll
  for (int nt = 0; nt < 4; ++nt) {
    const int row = nt * 16 + l15;
    const int swz = (row & 15) << 4;
#pragma unroll
    for (int mt = 0; mt < 2; ++mt) {
      const int ch0 = w * 32 + mt * 16 + lq * 4;
      float4 xv = make_float4(0.f, 0.f, 0.f, 0.f);
      if ((r0 + row) < N) xv = *(const float4*)(x + (size_t)(r0 + row) * 256 + ch0);
      ushort4 b4;
      b4.x = f2bf(reqf(xv.x + acc[mt][nt][0]));
      b4.y = f2bf(reqf(xv.y + acc[mt][nt][1]));
      b4.z = f2bf(reqf(xv.z + acc[mt][nt][2]));
      b4.w = f2bf(reqf(xv.w + acc[mt][nt][3]));
      *(ushort4*)((char*)sA + row * 512 + ((ch0 * 2) ^ swz)) = b4;
    }
  }
  __syncthreads();

  // ---- G5 (read-only on sA): up1, K=288 incl bin tail ----
  unsigned u1p[2][4][2];
  zero_acc(acc);
  gemm_ring<9, true>(g_wb + OFF_UP1, g_wb + OFF_PCONV, sW, sA, sBinA, w, l, l15, lq, acc);
  prelu_acc(acc, A_UP1);
#pragma unroll
  for (int i = 0; i < 2; ++i)
#pragma unroll
    for (int j = 0; j < 4; ++j)
#pragma unroll
      for (int p = 0; p < 2; ++p)
        u1p[i][j][p] = (unsigned)f2bf(acc[i][j][2 * p]) |
                       ((unsigned)f2bf(acc[i][j][2 * p + 1]) << 16);
  // no act barrier needed: G3 also only reads sA

  // ---- G3: pconv ----
  zero_acc(acc);
  gemm_ring<8, false>(g_wb + OFF_PCONV, g_wb + OFF_PLIN, sW, sA, sBinA, w, l, l15, lq, acc);
  prelu_acc(acc, A_PCONV);
  __syncthreads();
  stage_rq(acc, sA, w, l15, lq);
  __syncthreads();

  // ---- G4: plin -> cur_pred (255-stride: scalar stores) ----
  zero_acc(acc);
  gemm_ring<8, false>(g_wb + OFF_PLIN, g_wb + OFF_UR1, sW, sA, sBinA, w, l, l15, lq, acc);
#pragma unroll
  for (int nt = 0; nt < 4; ++nt) {
    const int row = nt * 16 + l15;
    if ((r0 + row) < N) {
      float* rp = out + PRED_BASE + (size_t)(r0 + row) * 255;
#pragma unroll
      for (int mt = 0; mt < 2; ++mt) {
        const int col0 = w * 32 + mt * 16 + lq * 4;
#pragma unroll
        for (int r = 0; r < 4; ++r)
          if (col0 + r < 255)
            rp[col0 + r] = acc[mt][nt][r];
      }
    }
  }
  __syncthreads();

  // ---- stage rq(u1) -> sA ----
#pragma unroll
  for (int nt = 0; nt < 4; ++nt) {
    const int row = nt * 16 + l15;
    const int swz = (row & 15) << 4;
#pragma unroll
    for (int mt = 0; mt < 2; ++mt) {
      const int ch2 = (w * 32 + mt * 16 + lq * 4) * 2;
      ushort4 b4;
      b4.x = f2bf(reqf(bf2f((unsigned short)(u1p[mt][nt][0]))));
      b4.y = f2bf(reqf(bf2f((unsigned short)(u1p[mt][nt][0] >> 16))));
      b4.z = f2bf(reqf(bf2f((unsigned short)(u1p[mt][nt][1]))));
      b4.w = f2bf(reqf(bf2f((unsigned short)(u1p[mt][nt][1] >> 16))));
      *(ushort4*)((char*)sA + row * 512 + (ch2 ^ swz)) = b4;
    }
  }
  __syncthreads();

  // ---- G6: ur1 ----
  zero_acc(acc);
  gemm_ring<8, false>(g_wb + OFF_UR1, g_wb + OFF_UR2, sW, sA, sBinA, w, l, l15, lq, acc);
  prelu_acc(acc, A_UR);
  __syncthreads();
  stage_rq(acc, sA, w, l15, lq);
  __syncthreads();

  // ---- G7: ur2 + residual (u = u1 + h), stage rq(u) -> sA ----
  zero_acc(acc);
  gemm_ring<8, false>(g_wb + OFF_UR2, g_wb + OFF_UOUT, sW, sA, sBinA, w, l, l15, lq, acc);
#pragma unroll
  for (int i = 0; i < 2; ++i)
#pragma unroll
    for (int j = 0; j < 4; ++j) {
      acc[i][j][0] += bf2f((unsigned short)(u1p[i][j][0]));
      acc[i][j][1] += bf2f((unsigned short)(u1p[i][j][0] >> 16));
      acc[i][j][2] += bf2f((unsigned short)(u1p[i][j][1]));
      acc[i][j][3] += bf2f((unsigned short)(u1p[i][j][1] >> 16));
    }
  __syncthreads();
  stage_rq(acc, sA, w, l15, lq);
  __syncthreads();

  // ---- G8: uout, 8 chunks (chunk c == child c); chained prefetch ----
#define G8_CHUNK(c, nextptr)                                                            \
  zero_acc(acc);                                                                        \
  gemm_ring<8, false>(g_wb + OFF_UOUT + (c) * 65536, nextptr, sW, sA, sBinA,            \
                      w, l, l15, lq, acc);                                              \
  store_chunk(acc, out, sBinA, r0, N, (c), w, l15, lq);

  G8_CHUNK(0, g_wb + OFF_UOUT + 1 * 65536)
  G8_CHUNK(1, g_wb + OFF_UOUT + 2 * 65536)
  G8_CHUNK(2, g_wb + OFF_UOUT + 3 * 65536)
  G8_CHUNK(3, g_wb + OFF_UOUT + 4 * 65536)
  G8_CHUNK(4, g_wb + OFF_UOUT + 5 * 65536)
  G8_CHUNK(5, g_wb + OFF_UOUT + 6 * 65536)
  G8_CHUNK(6, g_wb + OFF_UOUT + 7 * 65536)
  G8_CHUNK(7, (const unsigned short*)nullptr)
#undef G8_CHUNK
}

extern "C" void kernel_launch(void* const* d_in, const int* in_sizes, int n_in,
                              void* d_out, int out_size, void* d_ws, size_t ws_size,
                              hipStream_t stream) {
  const float* x        = (const float*)d_in[0];
  const int*   cur_bin  = (const int*)d_in[1];
  const float* w_dec1   = (const float*)d_in[2];
  const float* w_dec2   = (const float*)d_in[3];
  const float* a_dec    = (const float*)d_in[4];
  const float* w_pconv  = (const float*)d_in[5];
  const float* a_pconv  = (const float*)d_in[6];
  const float* w_plin   = (const float*)d_in[7];
  const float* w_up1    = (const float*)d_in[8];
  const float* a_up1    = (const float*)d_in[9];
  const float* w_ur1    = (const float*)d_in[10];
  const float* w_ur2    = (const float*)d_in[11];
  const float* a_ur     = (const float*)d_in[12];
  const float* w_uout   = (const float*)d_in[13];

  const int N = in_sizes[0] / 256;

  wconv_kernel<<<(WB_TOTAL + 255) / 256, 256, 0, stream>>>(
      w_dec1, w_dec2, w_pconv, w_plin, w_up1, w_ur1, w_ur2, w_uout);

  fused_kernel<<<(N + 63) / 64, 512, 0, stream>>>(
      x, cur_bin, a_dec, a_pconv, a_up1, a_ur, (float*)d_out, N);
}

// Round 16
// 277.444 us; speedup vs baseline: 1.5360x; 1.5360x over previous
//
#include <hip/hip_runtime.h>

typedef __bf16 bf16x8 __attribute__((ext_vector_type(8)));
typedef float  f32x4  __attribute__((ext_vector_type(4)));

// ---- weight regions in g_wb (bf16 element offsets), repacked into 16KB k-slices,
// each split into two 8KB mt-HALVES ----
// Slice s, half h holds W[m][k] for m = w*32 + h*16 + l15, k = s*32 + lq*8 + kk at
// j = h*4096 + w*512 + lq*128 + l15*8 + kk (j within the 8192-short slice).
// Wave-ownership invariant (8 waves): wave w DMAs half bytes [w*1024, +1024) and reads
// exactly those bytes back -> no barriers for weight staging, only per-wave counted vmcnt.
// Pipeline: 2-slot LDS ring of halves (depth-1, vmcnt(1)); 52 KB LDS -> 3 blocks/CU
// PROVIDED natural VGPR <= 84 (r14: 64). NO restrictive launch_bounds (r12/r15 lesson:
// a cap below natural allocation spills catastrophically).
#define OFF_DEC1  0
#define OFF_DEC2  65536
#define OFF_PCONV 131072
#define OFF_PLIN  196608   // rows >=255 zeroed (w_plin is 255x256)
#define OFF_UP1   262144   // 9 slices (K=288, k>=264 zeroed; w_up1 is 256x264)
#define OFF_UR1   335872
#define OFF_UR2   401408
#define OFF_UOUT  466944   // 8 chunks x 8 slices (chunk c = w_uout rows c*256..c*256+255)
#define WB_TOTAL  991232

__device__ __align__(16) unsigned short g_wb[WB_TOTAL];

__device__ __forceinline__ unsigned short f2bf(float f) {
  union { float f; unsigned u; } c; c.f = f;
  unsigned u = c.u + 0x7FFFu + ((c.u >> 16) & 1u);   // RNE, finite inputs only
  return (unsigned short)(u >> 16);
}
__device__ __forceinline__ float bf2f(unsigned short b) {
  union { unsigned u; float f; } c; c.u = ((unsigned)b) << 16;
  return c.f;
}
__device__ __forceinline__ float reqf(float v) {      // requant: x/256 clipped to int8 range
  return fminf(fmaxf(v * 0.00390625f, -128.f), 127.f);
}

// ---- weight fp32 -> bf16 preconvert + half-slice repack (runs every launch) ----
__global__ void wconv_kernel(const float* __restrict__ wd1, const float* __restrict__ wd2,
                             const float* __restrict__ wpc, const float* __restrict__ wpl,
                             const float* __restrict__ wu1, const float* __restrict__ wr1,
                             const float* __restrict__ wr2, const float* __restrict__ wuo) {
  int t = blockIdx.x * 256 + threadIdx.x;
  if (t >= WB_TOTAL) return;
  const float* src; int local, Ksrc = 256, Msrc = 256, rowOff = 0;
  if      (t < OFF_DEC2)  { src = wd1; local = t; }
  else if (t < OFF_PCONV) { src = wd2; local = t - OFF_DEC2; }
  else if (t < OFF_PLIN)  { src = wpc; local = t - OFF_PCONV; }
  else if (t < OFF_UP1)   { src = wpl; local = t - OFF_PLIN; Msrc = 255; }
  else if (t < OFF_UR1)   { src = wu1; local = t - OFF_UP1; Ksrc = 264; }
  else if (t < OFF_UR2)   { src = wr1; local = t - OFF_UR1; }
  else if (t < OFF_UOUT)  { src = wr2; local = t - OFF_UR2; }
  else { local = t - OFF_UOUT; int c = local >> 16; local &= 65535; src = wuo; rowOff = c * 256; }
  const int s = local >> 13, j = local & 8191;
  const int h = j >> 12, wv = (j >> 9) & 7, lq = (j >> 7) & 3;
  const int l15 = (j >> 3) & 15, kk = j & 7;
  const int m = wv * 32 + h * 16 + l15;
  const int k = s * 32 + lq * 8 + kk;
  float v = (m < Msrc && k < Ksrc) ? src[(size_t)(rowOff + m) * Ksrc + k] : 0.f;
  g_wb[t] = f2bf(v);
}

// ---- MFMA mapping (weights = A, acts = B) ----
// D-frag: col = l15 -> ACT ROW ; row = lq*4 + r -> OUTPUT CHANNEL offset within mt-block
// LDS act tile [64][256] bf16, byte = row*512 + (colbyte ^ ((row&15)<<4))
// (16-slot swizzle: r15 measured bank conflicts 16.1M -> 4.1M vs (row&7))

__device__ __forceinline__ void zero_acc(f32x4 (&acc)[2][4]) {
#pragma unroll
  for (int i = 0; i < 2; ++i)
#pragma unroll
    for (int j = 0; j < 4; ++j) acc[i][j] = (f32x4){0.f, 0.f, 0.f, 0.f};
}

__device__ __forceinline__ void prelu_acc(f32x4 (&acc)[2][4], float a) {
#pragma unroll
  for (int i = 0; i < 2; ++i)
#pragma unroll
    for (int j = 0; j < 4; ++j)
#pragma unroll
      for (int r = 0; r < 4; ++r) {
        float v = acc[i][j][r];
        acc[i][j][r] = v >= 0.f ? v : a * v;
      }
}

// DMA one 8 KB weight HALF into LDS: per wave, 1 issue x 64 lanes x 16 B into the
// wave's own 1 KB region (shorts [w*512, +512)).
__device__ __forceinline__ void stageWh(const unsigned short* __restrict__ src,
                                        unsigned short* dst, int w, int l) {
  const int off = w * 512 + l * 8;
  __builtin_amdgcn_global_load_lds(
      (const __attribute__((address_space(1))) unsigned*)(src + off),
      (__attribute__((address_space(3))) unsigned*)(dst + off),
      16, 0, 0);
}

// Full GEMM over NKS slices = 2*NKS half-steps on a 2-slot ring, 1 half in flight.
// Each GEMM has an even number of half-steps, so every GEMM's half 0 lands in slot 0.
// wnext = next GEMM's half-0 source (prefetch chains across GEMMs), or nullptr.
template<int NKS, bool BIN_TAIL>
__device__ __forceinline__ void gemm_ring(const unsigned short* __restrict__ wcur,
                                          const unsigned short* __restrict__ wnext,
                                          unsigned short* sW,
                                          const unsigned short* sAct,
                                          const unsigned short* sBinA,
                                          int w, int l, int l15, int lq,
                                          f32x4 (&acc)[2][4]) {
  bf16x8 af[4];
#pragma unroll
  for (int hs = 0; hs < 2 * NKS; ++hs) {
    const int ks = hs >> 1, mt = hs & 1;
    const int slot = hs & 1, nslot = slot ^ 1;
    if (hs + 1 < 2 * NKS) {
      stageWh(wcur + (hs + 1) * 4096, sW + nslot * 4096, w, l);
      asm volatile("s_waitcnt vmcnt(1)" ::: "memory");   // half hs landed; hs+1 in flight
    } else if (wnext) {
      stageWh(wnext, sW + nslot * 4096, w, l);
      asm volatile("s_waitcnt vmcnt(1)" ::: "memory");
    } else {
      asm volatile("s_waitcnt vmcnt(0)" ::: "memory");   // final GEMM tail: drain
    }
    __builtin_amdgcn_sched_barrier(0);
    if (mt == 0) {     // act fragments serve both halves of a slice
      if (BIN_TAIL && ks == NKS - 1) {
#pragma unroll
        for (int nt = 0; nt < 4; ++nt)
          af[nt] = *(const bf16x8*)(sBinA + (nt * 16 + l15) * 32 + lq * 8);
      } else {
        const int kb = ks * 64 + lq * 16;
#pragma unroll
        for (int nt = 0; nt < 4; ++nt) {
          const int row = nt * 16 + l15;
          af[nt] = *(const bf16x8*)((const char*)sAct + row * 512 + (kb ^ ((row & 15) << 4)));
        }
      }
    }
    __builtin_amdgcn_s_setprio(1);
    bf16x8 bfr = *(const bf16x8*)(sW + slot * 4096 + w * 512 + lq * 128 + l15 * 8);
#pragma unroll
    for (int nt = 0; nt < 4; ++nt)
      acc[mt][nt] = __builtin_amdgcn_mfma_f32_16x16x32_bf16(bfr, af[nt], acc[mt][nt], 0, 0, 0);
    __builtin_amdgcn_s_setprio(0);
  }
}

// acc -> requant -> bf16 -> swizzled LDS act tile; one ds_write_b64 per (nt,mt)
__device__ __forceinline__ void stage_rq(const f32x4 (&acc)[2][4], unsigned short* dst,
                                         int w, int l15, int lq) {
#pragma unroll
  for (int nt = 0; nt < 4; ++nt) {
    const int row = nt * 16 + l15;
    const int swz = (row & 15) << 4;
#pragma unroll
    for (int mt = 0; mt < 2; ++mt) {
      const int ch2 = (w * 32 + mt * 16 + lq * 4) * 2;   // byte offset (8B aligned)
      ushort4 b4;
      b4.x = f2bf(reqf(acc[mt][nt][0]));
      b4.y = f2bf(reqf(acc[mt][nt][1]));
      b4.z = f2bf(reqf(acc[mt][nt][2]));
      b4.w = f2bf(reqf(acc[mt][nt][3]));
      *(ushort4*)((char*)dst + row * 512 + (ch2 ^ swz)) = b4;
    }
  }
}

// uout chunk epilogue: mask by bin, f32x4 stores
__device__ __forceinline__ void store_chunk(const f32x4 (&acc)[2][4], float* __restrict__ out,
                                            const unsigned short* sBinA, int r0, int N,
                                            int c, int w, int l15, int lq) {
#pragma unroll
  for (int nt = 0; nt < 4; ++nt) {
    const int row = nt * 16 + l15;
    if ((r0 + row) < N) {
      const float m = sBinA[row * 32 + c] ? 1.f : 0.f;
      float* rp = out + (size_t)(r0 + row) * 2048 + c * 256;
#pragma unroll
      for (int mt = 0; mt < 2; ++mt) {
        const int ch0 = w * 32 + mt * 16 + lq * 4;
        f32x4 v;
        v[0] = acc[mt][nt][0] * m; v[1] = acc[mt][nt][1] * m;
        v[2] = acc[mt][nt][2] * m; v[3] = acc[mt][nt][3] * m;
        *(f32x4*)(rp + ch0) = v;
      }
    }
  }
}

__global__ __launch_bounds__(512, 4) void fused_kernel(
    const float* __restrict__ x, const int* __restrict__ cur_bin,
    const float* __restrict__ a_dec, const float* __restrict__ a_pconv,
    const float* __restrict__ a_up1, const float* __restrict__ a_ur,
    float* __restrict__ out, int N)
{
  __shared__ __align__(16) unsigned short sA[64 * 256];     // 32 KB act buffer (in place)
  __shared__ __align__(16) unsigned short sW[2 * 4096];     // 16 KB: 2-slot half ring
  __shared__ __align__(16) unsigned short sBinA[64 * 32];   // bin tile, k>=8 zeroed (4 KB)
  // total 52 KB; if natural VGPR <= 84 (r14: 64) runtime occupancy = 3 blocks/CU

  const int tid = threadIdx.x;
  const int w = tid >> 6, l = tid & 63;
  const int l15 = l & 15, lq = l >> 4;
  const int r0 = blockIdx.x * 64;
  const size_t PRED_BASE = (size_t)N * 2048;
  const size_t OCT_BASE  = PRED_BASE + (size_t)N * 255;

  const float A_DEC = a_dec[0], A_PCONV = a_pconv[0], A_UP1 = a_up1[0], A_UR = a_ur[0];

  // prologue: G1 half 0 into ring slot 0; overlaps act staging below
  stageWh(g_wb + OFF_DEC1, sW, w, l);

  // ---- stage bin (bf16-padded B-tile; 0/1 values exact in bf16) ----
  for (int i = tid; i < 64 * 32; i += 512) {
    const int row = i >> 5, j = i & 31;
    float bv = 0.f;
    if (j < 8 && (r0 + row) < N) bv = (float)cur_bin[(size_t)(r0 + row) * 8 + j];
    sBinA[i] = (j < 8) ? f2bf(bv) : (unsigned short)0;
  }
  // ---- cur_oct ----
  if (tid < 64 && (r0 + tid) < N) {
    int s = 0;
#pragma unroll
    for (int j = 0; j < 8; ++j) s += cur_bin[(size_t)(r0 + tid) * 8 + j] << j;
    out[OCT_BASE + r0 + tid] = (float)(s - 1);
  }
  // ---- stage requant(x) -> sA ----
#pragma unroll
  for (int it = 0; it < 8; ++it) {
    const int e = it * 2048 + tid * 4;
    const int row = e >> 8, col = e & 255;
    float4 xv = make_float4(0.f, 0.f, 0.f, 0.f);
    if ((r0 + row) < N) xv = *(const float4*)(x + (size_t)(r0 + row) * 256 + col);
    ushort4 b4;
    b4.x = f2bf(reqf(xv.x)); b4.y = f2bf(reqf(xv.y));
    b4.z = f2bf(reqf(xv.z)); b4.w = f2bf(reqf(xv.w));
    *(ushort4*)((char*)sA + row * 512 + ((col * 2) ^ ((row & 15) << 4))) = b4;
  }
  __syncthreads();   // drains prologue DMA + act/bin visibility

  f32x4 acc[2][4];

  // ---- G1: dec1 ----
  zero_acc(acc);
  gemm_ring<8, false>(g_wb + OFF_DEC1, g_wb + OFF_DEC2, sW, sA, sBinA, w, l, l15, lq, acc);
  prelu_acc(acc, A_DEC);
  __syncthreads();
  stage_rq(acc, sA, w, l15, lq);
  __syncthreads();

  // ---- G2: dec2 + residual -> rec, stage rq(rec) -> sA ----
  zero_acc(acc);
  gemm_ring<8, false>(g_wb + OFF_DEC2, g_wb + OFF_UP1, sW, sA, sBinA, w, l, l15, lq, acc);
  __syncthreads();
#pragma unroll
  for (int nt = 0; nt < 4; ++nt) {
    const int row = nt * 16 + l15;
    const int swz = (row & 15) << 4;
#pragma unroll
    for (int mt = 0; mt < 2; ++mt) {
      const int ch0 = w * 32 + mt * 16 + lq * 4;
      float4 xv = make_float4(0.f, 0.f, 0.f, 0.f);
      if ((r0 + row) < N) xv = *(const float4*)(x + (size_t)(r0 + row) * 256 + ch0);
      ushort4 b4;
      b4.x = f2bf(reqf(xv.x + acc[mt][nt][0]));
      b4.y = f2bf(reqf(xv.y + acc[mt][nt][1]));
      b4.z = f2bf(reqf(xv.z + acc[mt][nt][2]));
      b4.w = f2bf(reqf(xv.w + acc[mt][nt][3]));
      *(ushort4*)((char*)sA + row * 512 + ((ch0 * 2) ^ swz)) = b4;
    }
  }
  __syncthreads();

  // ---- G5 (read-only on sA): up1, K=288 incl bin tail ----
  unsigned u1p[2][4][2];
  zero_acc(acc);
  gemm_ring<9, true>(g_wb + OFF_UP1, g_wb + OFF_PCONV, sW, sA, sBinA, w, l, l15, lq, acc);
  prelu_acc(acc, A_UP1);
#pragma unroll
  for (int i = 0; i < 2; ++i)
#pragma unroll
    for (int j = 0; j < 4; ++j)
#pragma unroll
      for (int p = 0; p < 2; ++p)
        u1p[i][j][p] = (unsigned)f2bf(acc[i][j][2 * p]) |
                       ((unsigned)f2bf(acc[i][j][2 * p + 1]) << 16);
  // no act barrier needed: G3 also only reads sA

  // ---- G3: pconv ----
  zero_acc(acc);
  gemm_ring<8, false>(g_wb + OFF_PCONV, g_wb + OFF_PLIN, sW, sA, sBinA, w, l, l15, lq, acc);
  prelu_acc(acc, A_PCONV);
  __syncthreads();
  stage_rq(acc, sA, w, l15, lq);
  __syncthreads();

  // ---- G4: plin -> cur_pred (255-stride: scalar stores) ----
  zero_acc(acc);
  gemm_ring<8, false>(g_wb + OFF_PLIN, g_wb + OFF_UR1, sW, sA, sBinA, w, l, l15, lq, acc);
#pragma unroll
  for (int nt = 0; nt < 4; ++nt) {
    const int row = nt * 16 + l15;
    if ((r0 + row) < N) {
      float* rp = out + PRED_BASE + (size_t)(r0 + row) * 255;
#pragma unroll
      for (int mt = 0; mt < 2; ++mt) {
        const int col0 = w * 32 + mt * 16 + lq * 4;
#pragma unroll
        for (int r = 0; r < 4; ++r)
          if (col0 + r < 255)
            rp[col0 + r] = acc[mt][nt][r];
      }
    }
  }
  __syncthreads();

  // ---- stage rq(u1) -> sA ----
#pragma unroll
  for (int nt = 0; nt < 4; ++nt) {
    const int row = nt * 16 + l15;
    const int swz = (row & 15) << 4;
#pragma unroll
    for (int mt = 0; mt < 2; ++mt) {
      const int ch2 = (w * 32 + mt * 16 + lq * 4) * 2;
      ushort4 b4;
      b4.x = f2bf(reqf(bf2f((unsigned short)(u1p[mt][nt][0]))));
      b4.y = f2bf(reqf(bf2f((unsigned short)(u1p[mt][nt][0] >> 16))));
      b4.z = f2bf(reqf(bf2f((unsigned short)(u1p[mt][nt][1]))));
      b4.w = f2bf(reqf(bf2f((unsigned short)(u1p[mt][nt][1] >> 16))));
      *(ushort4*)((char*)sA + row * 512 + (ch2 ^ swz)) = b4;
    }
  }
  __syncthreads();

  // ---- G6: ur1 ----
  zero_acc(acc);
  gemm_ring<8, false>(g_wb + OFF_UR1, g_wb + OFF_UR2, sW, sA, sBinA, w, l, l15, lq, acc);
  prelu_acc(acc, A_UR);
  __syncthreads();
  stage_rq(acc, sA, w, l15, lq);
  __syncthreads();

  // ---- G7: ur2 + residual (u = u1 + h), stage rq(u) -> sA ----
  zero_acc(acc);
  gemm_ring<8, false>(g_wb + OFF_UR2, g_wb + OFF_UOUT, sW, sA, sBinA, w, l, l15, lq, acc);
#pragma unroll
  for (int i = 0; i < 2; ++i)
#pragma unroll
    for (int j = 0; j < 4; ++j) {
      acc[i][j][0] += bf2f((unsigned short)(u1p[i][j][0]));
      acc[i][j][1] += bf2f((unsigned short)(u1p[i][j][0] >> 16));
      acc[i][j][2] += bf2f((unsigned short)(u1p[i][j][1]));
      acc[i][j][3] += bf2f((unsigned short)(u1p[i][j][1] >> 16));
    }
  __syncthreads();
  stage_rq(acc, sA, w, l15, lq);
  __syncthreads();

  // ---- G8: uout, 8 chunks (chunk c == child c); chained prefetch ----
#define G8_CHUNK(c, nextptr)                                                            \
  zero_acc(acc);                                                                        \
  gemm_ring<8, false>(g_wb + OFF_UOUT + (c) * 65536, nextptr, sW, sA, sBinA,            \
                      w, l, l15, lq, acc);                                              \
  store_chunk(acc, out, sBinA, r0, N, (c), w, l15, lq);

  G8_CHUNK(0, g_wb + OFF_UOUT + 1 * 65536)
  G8_CHUNK(1, g_wb + OFF_UOUT + 2 * 65536)
  G8_CHUNK(2, g_wb + OFF_UOUT + 3 * 65536)
  G8_CHUNK(3, g_wb + OFF_UOUT + 4 * 65536)
  G8_CHUNK(4, g_wb + OFF_UOUT + 5 * 65536)
  G8_CHUNK(5, g_wb + OFF_UOUT + 6 * 65536)
  G8_CHUNK(6, g_wb + OFF_UOUT + 7 * 65536)
  G8_CHUNK(7, (const unsigned short*)nullptr)
#undef G8_CHUNK
}

extern "C" void kernel_launch(void* const* d_in, const int* in_sizes, int n_in,
                              void* d_out, int out_size, void* d_ws, size_t ws_size,
                              hipStream_t stream) {
  const float* x        = (const float*)d_in[0];
  const int*   cur_bin  = (const int*)d_in[1];
  const float* w_dec1   = (const float*)d_in[2];
  const float* w_dec2   = (const float*)d_in[3];
  const float* a_dec    = (const float*)d_in[4];
  const float* w_pconv  = (const float*)d_in[5];
  const float* a_pconv  = (const float*)d_in[6];
  const float* w_plin   = (const float*)d_in[7];
  const float* w_up1    = (const float*)d_in[8];
  const float* a_up1    = (const float*)d_in[9];
  const float* w_ur1    = (const float*)d_in[10];
  const float* w_ur2    = (const float*)d_in[11];
  const float* a_ur     = (const float*)d_in[12];
  const float* w_uout   = (const float*)d_in[13];

  const int N = in_sizes[0] / 256;

  wconv_kernel<<<(WB_TOTAL + 255) / 256, 256, 0, stream>>>(
      w_dec1, w_dec2, w_pconv, w_plin, w_up1, w_ur1, w_ur2, w_uout);

  fused_kernel<<<(N + 63) / 64, 512, 0, stream>>>(
      x, cur_bin, a_dec, a_pconv, a_up1, a_ur, (float*)d_out, N);
}

// Round 17
// 244.120 us; speedup vs baseline: 1.7457x; 1.1365x over previous
//
#include <hip/hip_runtime.h>

typedef __bf16 bf16x8 __attribute__((ext_vector_type(8)));
typedef float  f32x4  __attribute__((ext_vector_type(4)));

// ---- weight regions in g_wb (bf16 element offsets), repacked into 16KB k-slices ----
// Slice s holds W[m][k] for k = s*32 + lq*8 + kk, laid out [8 w][4 lq][2 mt][16 l15][8 kk]
// (j = w*1024 + lq*256 + mt*128 + l15*8 + kk, m = w*32 + mt*16 + l15).
// Wave-ownership invariant (8 waves): wave w DMAs slice bytes [w*2048, +2048) and reads
// exactly those bytes back -> weight staging needs NO barriers, only counted vmcnt waits.
// r10 structure (246us, best measured) + (row&15) act swizzle (r15->r16: conflicts /4).
#define OFF_DEC1  0
#define OFF_DEC2  65536
#define OFF_PCONV 131072
#define OFF_PLIN  196608   // rows >=255 zeroed (w_plin is 255x256)
#define OFF_UP1   262144   // 9 slices (K=288, k>=264 zeroed; w_up1 is 256x264)
#define OFF_UR1   335872
#define OFF_UR2   401408
#define OFF_UOUT  466944   // 8 chunks x 8 slices (chunk c = w_uout rows c*256..c*256+255)
#define WB_TOTAL  991232

__device__ __align__(16) unsigned short g_wb[WB_TOTAL];

__device__ __forceinline__ unsigned short f2bf(float f) {
  union { float f; unsigned u; } c; c.f = f;
  unsigned u = c.u + 0x7FFFu + ((c.u >> 16) & 1u);   // RNE, finite inputs only
  return (unsigned short)(u >> 16);
}
__device__ __forceinline__ float bf2f(unsigned short b) {
  union { unsigned u; float f; } c; c.u = ((unsigned)b) << 16;
  return c.f;
}
__device__ __forceinline__ float reqf(float v) {      // requant: x/256 clipped to int8 range
  return fminf(fmaxf(v * 0.00390625f, -128.f), 127.f);
}

// ---- weight fp32 -> bf16 preconvert + slice repack (runs every launch) ----
__global__ void wconv_kernel(const float* __restrict__ wd1, const float* __restrict__ wd2,
                             const float* __restrict__ wpc, const float* __restrict__ wpl,
                             const float* __restrict__ wu1, const float* __restrict__ wr1,
                             const float* __restrict__ wr2, const float* __restrict__ wuo) {
  int t = blockIdx.x * 256 + threadIdx.x;
  if (t >= WB_TOTAL) return;
  const float* src; int local, Ksrc = 256, Msrc = 256, rowOff = 0;
  if      (t < OFF_DEC2)  { src = wd1; local = t; }
  else if (t < OFF_PCONV) { src = wd2; local = t - OFF_DEC2; }
  else if (t < OFF_PLIN)  { src = wpc; local = t - OFF_PCONV; }
  else if (t < OFF_UP1)   { src = wpl; local = t - OFF_PLIN; Msrc = 255; }
  else if (t < OFF_UR1)   { src = wu1; local = t - OFF_UP1; Ksrc = 264; }
  else if (t < OFF_UR2)   { src = wr1; local = t - OFF_UR1; }
  else if (t < OFF_UOUT)  { src = wr2; local = t - OFF_UR2; }
  else { local = t - OFF_UOUT; int c = local >> 16; local &= 65535; src = wuo; rowOff = c * 256; }
  const int s = local >> 13, j = local & 8191;
  const int wv = j >> 10, lq = (j >> 8) & 3, mt = (j >> 7) & 1;
  const int l15 = (j >> 3) & 15, kk = j & 7;
  const int m = wv * 32 + mt * 16 + l15;
  const int k = s * 32 + lq * 8 + kk;
  float v = (m < Msrc && k < Ksrc) ? src[(size_t)(rowOff + m) * Ksrc + k] : 0.f;
  g_wb[t] = f2bf(v);
}

// ---- MFMA mapping (weights = A, acts = B) ----
// D-frag: col = l15 -> ACT ROW ; row = lq*4 + r -> OUTPUT CHANNEL offset within mt-block
// LDS act tile [64][256] bf16, byte = row*512 + (colbyte ^ ((row&15)<<4))
// (16-slot swizzle: measured conflicts 16.1M -> 4.1M vs (row&7), r15->r16)

__device__ __forceinline__ void zero_acc(f32x4 (&acc)[2][4]) {
#pragma unroll
  for (int i = 0; i < 2; ++i)
#pragma unroll
    for (int j = 0; j < 4; ++j) acc[i][j] = (f32x4){0.f, 0.f, 0.f, 0.f};
}

__device__ __forceinline__ void prelu_acc(f32x4 (&acc)[2][4], float a) {
#pragma unroll
  for (int i = 0; i < 2; ++i)
#pragma unroll
    for (int j = 0; j < 4; ++j)
#pragma unroll
      for (int r = 0; r < 4; ++r) {
        float v = acc[i][j][r];
        acc[i][j][r] = v >= 0.f ? v : a * v;
      }
}

// DMA one 16 KB weight slice into LDS: per wave, 2 issues x 64 lanes x 16 B into the
// wave's own 2 KB region (shorts [w*1024, +1024)).
__device__ __forceinline__ void stageW(const unsigned short* __restrict__ src,
                                       unsigned short* dst, int w, int l) {
#pragma unroll
  for (int i = 0; i < 2; ++i) {
    const int off = w * 1024 + i * 512 + l * 8;
    __builtin_amdgcn_global_load_lds(
        (const __attribute__((address_space(1))) unsigned*)(src + off),
        (__attribute__((address_space(3))) unsigned*)(dst + off),
        16, 0, 0);
  }
}

// one 32-k slice of C += W(A) @ act(B)
__device__ __forceinline__ void mfma_slice(const unsigned short* wl, const unsigned short* sAct,
                                           int w, int l15, int lq, int kb, f32x4 (&acc)[2][4]) {
  bf16x8 af[4];
#pragma unroll
  for (int nt = 0; nt < 4; ++nt) {
    const int row = nt * 16 + l15;
    af[nt] = *(const bf16x8*)((const char*)sAct + row * 512 + (kb ^ ((row & 15) << 4)));
  }
#pragma unroll
  for (int mt = 0; mt < 2; ++mt) {
    bf16x8 bfr = *(const bf16x8*)(wl + w * 1024 + lq * 256 + mt * 128 + l15 * 8);
#pragma unroll
    for (int nt = 0; nt < 4; ++nt)
      acc[mt][nt] = __builtin_amdgcn_mfma_f32_16x16x32_bf16(bfr, af[nt], acc[mt][nt], 0, 0, 0);
  }
}

// Full GEMM over NKS slices, double-buffered weight DMA with COUNTED vmcnt waits.
template<int NKS, bool BIN_TAIL>
__device__ __forceinline__ void gemm_cnt(const unsigned short* __restrict__ wcur,
                                         const unsigned short* __restrict__ wnext,
                                         unsigned short*& wl, unsigned short*& wn,
                                         const unsigned short* sAct,
                                         const unsigned short* sBinA,
                                         int w, int l, int l15, int lq,
                                         f32x4 (&acc)[2][4]) {
#pragma unroll
  for (int ks = 0; ks < NKS; ++ks) {
    if (ks < NKS - 1) {
      stageW(wcur + (ks + 1) * 8192, wn, w, l);
      asm volatile("s_waitcnt vmcnt(2)" ::: "memory");   // slice ks landed; ks+1 in flight
    } else if (wnext) {
      stageW(wnext, wn, w, l);
      asm volatile("s_waitcnt vmcnt(2)" ::: "memory");
    } else {
      asm volatile("s_waitcnt vmcnt(0)" ::: "memory");   // final slice: nothing in flight
    }
    __builtin_amdgcn_sched_barrier(0);
    __builtin_amdgcn_s_setprio(1);
    if (BIN_TAIL && ks == NKS - 1) {
      bf16x8 af[4];
#pragma unroll
      for (int nt = 0; nt < 4; ++nt)
        af[nt] = *(const bf16x8*)(sBinA + (nt * 16 + l15) * 32 + lq * 8);
#pragma unroll
      for (int mt = 0; mt < 2; ++mt) {
        bf16x8 bfr = *(const bf16x8*)(wl + w * 1024 + lq * 256 + mt * 128 + l15 * 8);
#pragma unroll
        for (int nt = 0; nt < 4; ++nt)
          acc[mt][nt] = __builtin_amdgcn_mfma_f32_16x16x32_bf16(bfr, af[nt], acc[mt][nt], 0, 0, 0);
      }
    } else {
      mfma_slice(wl, sAct, w, l15, lq, ks * 64 + lq * 16, acc);
    }
    __builtin_amdgcn_s_setprio(0);
    unsigned short* t2 = wl; wl = wn; wn = t2;
  }
}

// acc -> requant -> bf16 -> swizzled LDS act tile; one ds_write_b64 per (nt,mt)
__device__ __forceinline__ void stage_rq(const f32x4 (&acc)[2][4], unsigned short* dst,
                                         int w, int l15, int lq) {
#pragma unroll
  for (int nt = 0; nt < 4; ++nt) {
    const int row = nt * 16 + l15;
    const int swz = (row & 15) << 4;
#pragma unroll
    for (int mt = 0; mt < 2; ++mt) {
      const int ch2 = (w * 32 + mt * 16 + lq * 4) * 2;   // byte offset (8B aligned)
      ushort4 b4;
      b4.x = f2bf(reqf(acc[mt][nt][0]));
      b4.y = f2bf(reqf(acc[mt][nt][1]));
      b4.z = f2bf(reqf(acc[mt][nt][2]));
      b4.w = f2bf(reqf(acc[mt][nt][3]));
      *(ushort4*)((char*)dst + row * 512 + (ch2 ^ swz)) = b4;
    }
  }
}

__global__ __launch_bounds__(512, 4) void fused_kernel(
    const float* __restrict__ x, const int* __restrict__ cur_bin,
    const float* __restrict__ a_dec, const float* __restrict__ a_pconv,
    const float* __restrict__ a_up1, const float* __restrict__ a_ur,
    float* __restrict__ out, int N)
{
  __shared__ __align__(16) unsigned short sA[64 * 256];     // 32 KB act buffer (in place)
  __shared__ __align__(16) unsigned short sW0[8192];        // 16 KB weight slice
  __shared__ __align__(16) unsigned short sW1[8192];        // 16 KB weight slice
  __shared__ __align__(16) unsigned short sBinA[64 * 32];   // bin tile, k>=8 zeroed (4 KB)

  const int tid = threadIdx.x;
  const int w = tid >> 6, l = tid & 63;
  const int l15 = l & 15, lq = l >> 4;
  const int r0 = blockIdx.x * 64;
  const size_t PRED_BASE = (size_t)N * 2048;
  const size_t OCT_BASE  = PRED_BASE + (size_t)N * 255;

  const float A_DEC = a_dec[0], A_PCONV = a_pconv[0], A_UP1 = a_up1[0], A_UR = a_ur[0];

  unsigned short *wl = sW0, *wn = sW1;
  stageW(g_wb + OFF_DEC1, wl, w, l);   // slice-0 DMA overlaps act staging

  // ---- stage bin (bf16-padded B-tile; 0/1 values exact in bf16) ----
  for (int i = tid; i < 64 * 32; i += 512) {
    const int row = i >> 5, j = i & 31;
    float bv = 0.f;
    if (j < 8 && (r0 + row) < N) bv = (float)cur_bin[(size_t)(r0 + row) * 8 + j];
    sBinA[i] = (j < 8) ? f2bf(bv) : (unsigned short)0;
  }
  // ---- cur_oct ----
  if (tid < 64 && (r0 + tid) < N) {
    int s = 0;
#pragma unroll
    for (int j = 0; j < 8; ++j) s += cur_bin[(size_t)(r0 + tid) * 8 + j] << j;
    out[OCT_BASE + r0 + tid] = (float)(s - 1);
  }
  // ---- stage requant(x) -> sA ----
#pragma unroll
  for (int it = 0; it < 8; ++it) {
    const int e = it * 2048 + tid * 4;
    const int row = e >> 8, col = e & 255;
    float4 xv = make_float4(0.f, 0.f, 0.f, 0.f);
    if ((r0 + row) < N) xv = *(const float4*)(x + (size_t)(r0 + row) * 256 + col);
    ushort4 b4;
    b4.x = f2bf(reqf(xv.x)); b4.y = f2bf(reqf(xv.y));
    b4.z = f2bf(reqf(xv.z)); b4.w = f2bf(reqf(xv.w));
    *(ushort4*)((char*)sA + row * 512 + ((col * 2) ^ ((row & 15) << 4))) = b4;
  }
  __syncthreads();   // drains slice-0 DMA + act/bin visibility

  f32x4 acc[2][4];

  // ---- G1: dec1 ----
  zero_acc(acc);
  gemm_cnt<8, false>(g_wb + OFF_DEC1, g_wb + OFF_DEC2, wl, wn, sA, sBinA, w, l, l15, lq, acc);
  prelu_acc(acc, A_DEC);
  __syncthreads();
  stage_rq(acc, sA, w, l15, lq);
  __syncthreads();

  // ---- G2: dec2 + residual -> rec, stage rq(rec) -> sA ----
  zero_acc(acc);
  gemm_cnt<8, false>(g_wb + OFF_DEC2, g_wb + OFF_UP1, wl, wn, sA, sBinA, w, l, l15, lq, acc);
  __syncthreads();
#pragma unroll
  for (int nt = 0; nt < 4; ++nt) {
    const int row = nt * 16 + l15;
    const int swz = (row & 15) << 4;
#pragma unroll
    for (int mt = 0; mt < 2; ++mt) {
      const int ch0 = w * 32 + mt * 16 + lq * 4;
      float4 xv = make_float4(0.f, 0.f, 0.f, 0.f);
      if ((r0 + row) < N) xv = *(const float4*)(x + (size_t)(r0 + row) * 256 + ch0);
      ushort4 b4;
      b4.x = f2bf(reqf(xv.x + acc[mt][nt][0]));
      b4.y = f2bf(reqf(xv.y + acc[mt][nt][1]));
      b4.z = f2bf(reqf(xv.z + acc[mt][nt][2]));
      b4.w = f2bf(reqf(xv.w + acc[mt][nt][3]));
      *(ushort4*)((char*)sA + row * 512 + ((ch0 * 2) ^ swz)) = b4;
    }
  }
  __syncthreads();

  // ---- G5 (read-only on sA): up1, K=288 incl bin tail ----
  unsigned u1p[2][4][2];
  zero_acc(acc);
  gemm_cnt<9, true>(g_wb + OFF_UP1, g_wb + OFF_PCONV, wl, wn, sA, sBinA, w, l, l15, lq, acc);
  prelu_acc(acc, A_UP1);
#pragma unroll
  for (int i = 0; i < 2; ++i)
#pragma unroll
    for (int j = 0; j < 4; ++j)
#pragma unroll
      for (int p = 0; p < 2; ++p)
        u1p[i][j][p] = (unsigned)f2bf(acc[i][j][2 * p]) |
                       ((unsigned)f2bf(acc[i][j][2 * p + 1]) << 16);
  // no act barrier needed: G3 also only reads sA

  // ---- G3: pconv ----
  zero_acc(acc);
  gemm_cnt<8, false>(g_wb + OFF_PCONV, g_wb + OFF_PLIN, wl, wn, sA, sBinA, w, l, l15, lq, acc);
  prelu_acc(acc, A_PCONV);
  __syncthreads();
  stage_rq(acc, sA, w, l15, lq);
  __syncthreads();

  // ---- G4: plin -> cur_pred (255-stride: scalar stores) ----
  zero_acc(acc);
  gemm_cnt<8, false>(g_wb + OFF_PLIN, g_wb + OFF_UR1, wl, wn, sA, sBinA, w, l, l15, lq, acc);
#pragma unroll
  for (int nt = 0; nt < 4; ++nt) {
    const int row = nt * 16 + l15;
    if ((r0 + row) < N) {
      float* rp = out + PRED_BASE + (size_t)(r0 + row) * 255;
#pragma unroll
      for (int mt = 0; mt < 2; ++mt) {
        const int col0 = w * 32 + mt * 16 + lq * 4;
#pragma unroll
        for (int r = 0; r < 4; ++r)
          if (col0 + r < 255)
            rp[col0 + r] = acc[mt][nt][r];
      }
    }
  }
  __syncthreads();

  // ---- stage rq(u1) -> sA ----
#pragma unroll
  for (int nt = 0; nt < 4; ++nt) {
    const int row = nt * 16 + l15;
    const int swz = (row & 15) << 4;
#pragma unroll
    for (int mt = 0; mt < 2; ++mt) {
      const int ch2 = (w * 32 + mt * 16 + lq * 4) * 2;
      ushort4 b4;
      b4.x = f2bf(reqf(bf2f((unsigned short)(u1p[mt][nt][0]))));
      b4.y = f2bf(reqf(bf2f((unsigned short)(u1p[mt][nt][0] >> 16))));
      b4.z = f2bf(reqf(bf2f((unsigned short)(u1p[mt][nt][1]))));
      b4.w = f2bf(reqf(bf2f((unsigned short)(u1p[mt][nt][1] >> 16))));
      *(ushort4*)((char*)sA + row * 512 + (ch2 ^ swz)) = b4;
    }
  }
  __syncthreads();

  // ---- G6: ur1 ----
  zero_acc(acc);
  gemm_cnt<8, false>(g_wb + OFF_UR1, g_wb + OFF_UR2, wl, wn, sA, sBinA, w, l, l15, lq, acc);
  prelu_acc(acc, A_UR);
  __syncthreads();
  stage_rq(acc, sA, w, l15, lq);
  __syncthreads();

  // ---- G7: ur2 + residual (u = u1 + h), stage rq(u) -> sA ----
  zero_acc(acc);
  gemm_cnt<8, false>(g_wb + OFF_UR2, g_wb + OFF_UOUT, wl, wn, sA, sBinA, w, l, l15, lq, acc);
#pragma unroll
  for (int i = 0; i < 2; ++i)
#pragma unroll
    for (int j = 0; j < 4; ++j) {
      acc[i][j][0] += bf2f((unsigned short)(u1p[i][j][0]));
      acc[i][j][1] += bf2f((unsigned short)(u1p[i][j][0] >> 16));
      acc[i][j][2] += bf2f((unsigned short)(u1p[i][j][1]));
      acc[i][j][3] += bf2f((unsigned short)(u1p[i][j][1] >> 16));
    }
  __syncthreads();
  stage_rq(acc, sA, w, l15, lq);
  __syncthreads();

  // ---- G8: uout, 8 chunks of 256 cols (chunk c == child c), f32x4 stores ----
#pragma unroll 1
  for (int c = 0; c < 8; ++c) {
    zero_acc(acc);
    const unsigned short* wnxt = (c < 7) ? (g_wb + OFF_UOUT + (c + 1) * 65536) : nullptr;
    gemm_cnt<8, false>(g_wb + OFF_UOUT + c * 65536, wnxt, wl, wn, sA, sBinA, w, l, l15, lq, acc);
#pragma unroll
    for (int nt = 0; nt < 4; ++nt) {
      const int row = nt * 16 + l15;
      if ((r0 + row) < N) {
        const float m = sBinA[row * 32 + c] ? 1.f : 0.f;
        float* rp = out + (size_t)(r0 + row) * 2048 + c * 256;
#pragma unroll
        for (int mt = 0; mt < 2; ++mt) {
          const int ch0 = w * 32 + mt * 16 + lq * 4;
          f32x4 v;
          v[0] = acc[mt][nt][0] * m; v[1] = acc[mt][nt][1] * m;
          v[2] = acc[mt][nt][2] * m; v[3] = acc[mt][nt][3] * m;
          *(f32x4*)(rp + ch0) = v;
        }
      }
    }
  }
}

extern "C" void kernel_launch(void* const* d_in, const int* in_sizes, int n_in,
                              void* d_out, int out_size, void* d_ws, size_t ws_size,
                              hipStream_t stream) {
  const float* x        = (const float*)d_in[0];
  const int*   cur_bin  = (const int*)d_in[1];
  const float* w_dec1   = (const float*)d_in[2];
  const float* w_dec2   = (const float*)d_in[3];
  const float* a_dec    = (const float*)d_in[4];
  const float* w_pconv  = (const float*)d_in[5];
  const float* a_pconv  = (const float*)d_in[6];
  const float* w_plin   = (const float*)d_in[7];
  const float* w_up1    = (const float*)d_in[8];
  const float* a_up1    = (const float*)d_in[9];
  const float* w_ur1    = (const float*)d_in[10];
  const float* w_ur2    = (const float*)d_in[11];
  const float* a_ur     = (const float*)d_in[12];
  const float* w_uout   = (const float*)d_in[13];

  const int N = in_sizes[0] / 256;

  wconv_kernel<<<(WB_TOTAL + 255) / 256, 256, 0, stream>>>(
      w_dec1, w_dec2, w_pconv, w_plin, w_up1, w_ur1, w_ur2, w_uout);

  fused_kernel<<<(N + 63) / 64, 512, 0, stream>>>(
      x, cur_bin, a_dec, a_pconv, a_up1, a_ur, (float*)d_out, N);
}